// Round 9
// baseline (309.916 us; speedup 1.0000x reference)
//
#include <hip/hip_runtime.h>
#include <hip/hip_bf16.h>

#define NROWS 16384
#define DIN   4096
#define DOUT  4096
#define RNK   64
#define EPSF  1e-7f

typedef float  f32x4  __attribute__((ext_vector_type(4)));
typedef __bf16 bf16x4 __attribute__((ext_vector_type(4)));
typedef __bf16 bf16x8 __attribute__((ext_vector_type(8)));

__device__ __forceinline__ bf16x8 cvt8(f32x4 a, f32x4 b) {
    bf16x8 r;
    r[0]=(__bf16)a.x; r[1]=(__bf16)a.y; r[2]=(__bf16)a.z; r[3]=(__bf16)a.w;
    r[4]=(__bf16)b.x; r[5]=(__bf16)b.y; r[6]=(__bf16)b.z; r[7]=(__bf16)b.w;
    return r;
}
__device__ __forceinline__ bf16x4 cvt4(f32x4 v) {
    bf16x4 r;
    r[0]=(__bf16)v.x; r[1]=(__bf16)v.y; r[2]=(__bf16)v.z; r[3]=(__bf16)v.w;
    return r;
}

// ---------------------------------------------------------------------------
// KA: Apf = Aw in bf16 MFMA-fragment order (for k1's B... A-operand).
// Chunk (kt, ng): Apf[(kt*4+ng)*512 + l*8 + j] = Aw[ng*16+(l&15)][kt*32+(l>>4)*8+j]
// ---------------------------------------------------------------------------
__global__ __launch_bounds__(512, 2)
void ka_apf(const float* __restrict__ Aw, __bf16* __restrict__ Apf) {
    const int kt = blockIdx.x;           // 128 K-chunks of 32
    const int t = threadIdx.x;
    const int ng = t >> 7, le = (t >> 1) & 63, h = t & 1;
    f32x4 v = *(const f32x4*)&Aw[(size_t)(ng*16 + (le&15)) * DIN + kt*32 + (le>>4)*8 + h*4];
    *(bf16x4*)&Apf[((size_t)(kt*4 + ng))*512 + le*8 + h*4] = cvt4(v);
}

// ---------------------------------------------------------------------------
// KB (round-2 verbatim): B -> bf16 plain copy + Gram partials (G = B^T B).
// ---------------------------------------------------------------------------
__global__ __launch_bounds__(512, 4)
void kb_gram(const float* __restrict__ Bw, __bf16* __restrict__ Bp,
             float* __restrict__ Gpart) {
    __shared__ __bf16 bs[256][72];
    const int t = threadIdx.x;
    const int jb = blockIdx.x * 256;
    {
        const int j0 = t >> 1, c0 = (t & 1) * 32;
        #pragma unroll
        for (int u = 0; u < 4; ++u) {
            f32x4 v0 = *(const f32x4*)&Bw[(size_t)(jb + j0) * RNK + c0 + 8*u];
            f32x4 v1 = *(const f32x4*)&Bw[(size_t)(jb + j0) * RNK + c0 + 8*u + 4];
            bf16x8 p = cvt8(v0, v1);
            *(bf16x8*)&bs[j0][c0 + 8*u] = p;
            *(bf16x8*)&Bp[(size_t)(jb + j0) * RNK + c0 + 8*u] = p;
        }
    }
    __syncthreads();
    const int r = t & 63, rp = (t >> 6) * 8;
    float acc[8] = {0,0,0,0,0,0,0,0};
    for (int j = 0; j < 256; ++j) {
        float s = (float)bs[j][r];
        bf16x8 v = *(const bf16x8*)&bs[j][rp];   // wave-uniform: broadcast
        #pragma unroll
        for (int u = 0; u < 8; ++u) acc[u] += s * (float)v[u];
    }
    #pragma unroll
    for (int u = 0; u < 8; ++u)
        Gpart[(size_t)blockIdx.x * 4096 + r * 64 + rp + u] = acc[u];
}

__global__ void kc0_sum(const float* __restrict__ Gpart, float* __restrict__ G) {
    const int t = threadIdx.x;
    #pragma unroll
    for (int v = 0; v < 4; ++v) {
        f32x4 a = {0.f, 0.f, 0.f, 0.f};
        for (int b = 0; b < 16; ++b)
            a += *(const f32x4*)&Gpart[(size_t)b * 4096 + t * 16 + v * 4];
        *(f32x4*)&G[t * 16 + v * 4] = a;
    }
}

// ---------------------------------------------------------------------------
// K1 (rebuilt): s1b = bf16( sinh(||x||)/||x|| * x @ Aw^T ).
// 1024 blocks x 256 thr. 16 rows/block; wave w owns K-quarter [w*1024,+1024),
// 8 tiles of K=128. CONTIGUOUS loads: 8 instrs/tile, each 2 rows x 512 B.
// Wave-private LDS transpose (288 B pitch), NO barriers in the K-loop.
// Apf fragments issued before next-tile x prefetch (vmcnt ordering).
// Epilogue: 2 barriers; partials overlay staging LDS (dead after barrier 1).
// ---------------------------------------------------------------------------
__global__ __launch_bounds__(256, 3)
void k1(const float* __restrict__ x, const __bf16* __restrict__ Apf,
        __bf16* __restrict__ s1b) {
    __shared__ __align__(16) char smem[37120];
    // staging: wave w at smem + w*9216 (2 buffers x 4608 B = 16 rows x 288 B)
    float (*part)[16][68] = (float (*)[16][68])(smem);        // overlay (after bar 1)
    float (*ssqs)[16]     = (float (*)[16])(smem + 36864);    // outside staging

    const int tid = threadIdx.x, l = tid & 63, w = tid >> 6;
    const int brow = blockIdx.x * 16;
    const int rlo = l >> 5;            // which of the 2 rows in a load instr
    const int c32 = (l & 31) * 4;      // f32x4 col within the 128-float tile

    __bf16* stg = (__bf16*)(smem + w * 9216);
    const size_t xbase = (size_t)brow * DIN + (size_t)w * 1024;

    f32x4 cur[8], nxt[8];
    f32x4 acc[4];
    #pragma unroll
    for (int n = 0; n < 4; ++n) acc[n] = (f32x4){0.f, 0.f, 0.f, 0.f};
    float ssqp[8] = {0.f,0.f,0.f,0.f,0.f,0.f,0.f,0.f};

    #pragma unroll
    for (int j = 0; j < 8; ++j)
        cur[j] = *(const f32x4*)&x[xbase + (size_t)(2*j + rlo) * DIN + c32];

    #pragma unroll
    for (int t = 0; t < 8; ++t) {
        // 1. Apf fragments for this tile (L2) — issued BEFORE x prefetch
        bf16x8 ap[16];
        #pragma unroll
        for (int kk = 0; kk < 4; ++kk) {
            #pragma unroll
            for (int ng = 0; ng < 4; ++ng) {
                const int kt = w * 32 + t * 4 + kk;
                ap[kk*4 + ng] = *(const bf16x8*)&Apf[((size_t)(kt*4 + ng))*512 + l*8];
            }
        }
        // 2. x prefetch: next tile, 8 x 1KB contiguous instrs (stays in flight)
        if (t < 7) {
            #pragma unroll
            for (int j = 0; j < 8; ++j)
                nxt[j] = *(const f32x4*)&x[xbase + (size_t)(2*j + rlo) * DIN
                                           + (size_t)(t+1)*128 + c32];
        }
        // 3. consume cur: ssq (f32) + cvt + wave-private LDS write
        __bf16* buf = stg + (t & 1) * 2304;   // elements (4608 B)
        #pragma unroll
        for (int j = 0; j < 8; ++j) {
            f32x4 v = cur[j];
            ssqp[j] += v.x*v.x + v.y*v.y + v.z*v.z + v.w*v.w;
            *(bf16x4*)&buf[(2*j + rlo) * 144 + c32] = cvt4(v);
        }
        // 4. fragment reads (same-wave, in-order ds) + MFMA
        #pragma unroll
        for (int kk = 0; kk < 4; ++kk) {
            bf16x8 af = *(const bf16x8*)&buf[(l & 15)*144 + kk*32 + (l >> 4)*8];
            #pragma unroll
            for (int ng = 0; ng < 4; ++ng)
                acc[ng] = __builtin_amdgcn_mfma_f32_16x16x32_bf16(ap[kk*4+ng], af,
                                                                  acc[ng], 0, 0, 0);
        }
        // 5. rotate
        if (t < 7) {
            #pragma unroll
            for (int j = 0; j < 8; ++j) cur[j] = nxt[j];
        }
    }

    // ssq: reduce across the 32 lanes owning each row
    #pragma unroll
    for (int j = 0; j < 8; ++j) {
        float v = ssqp[j];
        v += __shfl_xor(v, 1);  v += __shfl_xor(v, 2);  v += __shfl_xor(v, 4);
        v += __shfl_xor(v, 8);  v += __shfl_xor(v, 16);
        if ((l & 31) == 0) ssqs[w][2*j + rlo] = v;
    }
    __syncthreads();                    // staging dead; part[] may overlay

    const int rl = l & 15, ko = l >> 4;
    *(f32x4*)&part[w][rl][ 0 + ko*4] = acc[0];
    *(f32x4*)&part[w][rl][16 + ko*4] = acc[1];
    *(f32x4*)&part[w][rl][32 + ko*4] = acc[2];
    *(f32x4*)&part[w][rl][48 + ko*4] = acc[3];
    __syncthreads();

    // reduce 4 K-quarters + sinh scale; thread: row tid>>4, cols (tid&15)*4..+3
    const int row = tid >> 4, c4 = (tid & 15) * 4;
    f32x4 s = *(const f32x4*)&part[0][row][c4];
    s += *(const f32x4*)&part[1][row][c4];
    s += *(const f32x4*)&part[2][row][c4];
    s += *(const f32x4*)&part[3][row][c4];
    const float ssqt = ssqs[0][row] + ssqs[1][row] + ssqs[2][row] + ssqs[3][row];
    const float vn = fmaxf(sqrtf(ssqt), EPSF);
    const float sc = sinhf(vn) / vn;
    s *= sc;
    *(bf16x4*)&s1b[(size_t)(brow + row) * RNK + c4] = cvt4(s);
}

// ---------------------------------------------------------------------------
// KC (round-2, bf16 input): r2 = s1^T G s1 ; g = 0.25*acosh(...)/max(r,eps);
// s1p = bf16(g * s1). One wave per row, 8 rows/block.
// ---------------------------------------------------------------------------
__global__ __launch_bounds__(512, 4)
void kc_scale(const __bf16* __restrict__ s1b, const float* __restrict__ G,
              __bf16* __restrict__ s1p) {
    __shared__ float Gs[64][64];
    __shared__ float sr[8][64];
    const int t = threadIdx.x, l = t & 63, w = t >> 6;
    {
        float* gf = &Gs[0][0];
        *(f32x4*)&gf[t * 8]     = *(const f32x4*)&G[t * 8];
        *(f32x4*)&gf[t * 8 + 4] = *(const f32x4*)&G[t * 8 + 4];
    }
    const int row = blockIdx.x * 8 + w;
    const float a = (float)s1b[(size_t)row * RNK + l];
    sr[w][l] = a;
    __syncthreads();

    float y = 0.f;
    #pragma unroll 8
    for (int r = 0; r < 64; ++r) y += Gs[r][l] * sr[w][r];

    float q = a * y;
    q += __shfl_xor(q, 1);  q += __shfl_xor(q, 2);  q += __shfl_xor(q, 4);
    q += __shfl_xor(q, 8);  q += __shfl_xor(q, 16); q += __shfl_xor(q, 32);

    const float r2 = q;
    const float rn = sqrtf(r2);
    const float g = 0.25f * acoshf(fmaxf(sqrtf(1.f + r2), 1.f + EPSF))
                          / fmaxf(rn, EPSF);
    s1p[(size_t)row * RNK + l] = (__bf16)(g * a);
}

// ---------------------------------------------------------------------------
// K2 (round-2 verbatim): out = s1p @ Bp^T. 64x64 tile/block, 16384 blocks.
// ---------------------------------------------------------------------------
__global__ __launch_bounds__(512, 4)
void k2_gemm2(const __bf16* __restrict__ s1p, const __bf16* __restrict__ Bp,
              float* __restrict__ out) {
    __shared__ __bf16 ss[64][72];
    __shared__ __bf16 bsh[64][72];
    const int t = threadIdx.x, l = t & 63, w = t >> 6;
    const int rt = blockIdx.x >> 6;
    const int ct = blockIdx.x & 63;
    const int brow = rt * 64, bcol = ct * 64;

    {
        const int row = t >> 3, c = (t & 7) * 8;
        *(bf16x8*)&ss[row][c]  = *(const bf16x8*)&s1p[(size_t)(brow + row) * RNK + c];
        *(bf16x8*)&bsh[row][c] = *(const bf16x8*)&Bp[(size_t)(bcol + row) * RNK + c];
    }
    __syncthreads();

    const int m0 = (w & 3) * 16;
    const int n0 = (w >> 2) * 32;
    const int frow = l & 15;
    const int koff = (l >> 4) * 8;

    f32x4 a0 = {0.f,0.f,0.f,0.f}, a1 = {0.f,0.f,0.f,0.f};
    #pragma unroll
    for (int ks = 0; ks < 2; ++ks) {
        bf16x8 af = *(const bf16x8*)&ss[m0 + frow][ks*32 + koff];
        bf16x8 b0 = *(const bf16x8*)&bsh[n0 + frow][ks*32 + koff];
        bf16x8 b1 = *(const bf16x8*)&bsh[n0 + 16 + frow][ks*32 + koff];
        a0 = __builtin_amdgcn_mfma_f32_16x16x32_bf16(af, b0, a0, 0, 0, 0);
        a1 = __builtin_amdgcn_mfma_f32_16x16x32_bf16(af, b1, a1, 0, 0, 0);
    }

    #pragma unroll
    for (int q = 0; q < 4; ++q) {
        const int row = m0 + (l >> 4) * 4 + q;
        const size_t ob = (size_t)(brow + row) * DOUT + bcol;
        out[ob + n0 + frow]      = a0[q];
        out[ob + n0 + 16 + frow] = a1[q];
    }
}

extern "C" void kernel_launch(void* const* d_in, const int* in_sizes, int n_in,
                              void* d_out, int out_size, void* d_ws, size_t ws_size,
                              hipStream_t stream) {
    const float* x  = (const float*)d_in[0];   // (16384, 4096)
    const float* Aw = (const float*)d_in[1];   // (64, 4096)
    const float* Bw = (const float*)d_in[2];   // (4096, 64)
    float* out = (float*)d_out;

    char* ws = (char*)d_ws;
    __bf16* Apf   = (__bf16*)(ws);                  // 512 KB (fragment order)
    __bf16* Bp    = (__bf16*)(ws + 0x080000);       // 512 KB (plain bf16)
    float*  Gpart = (float*)(ws + 0x100000);        // 256 KB
    float*  G     = (float*)(ws + 0x140000);        // 16 KB
    __bf16* s1b   = (__bf16*)(ws + 0x150000);       // 2 MB (sinh-scaled s1, bf16)
    __bf16* s1p   = (__bf16*)(ws + 0x350000);       // 2 MB (g-scaled, bf16)

    ka_apf<<<128, 512, 0, stream>>>(Aw, Apf);
    kb_gram<<<16, 512, 0, stream>>>(Bw, Bp, Gpart);
    kc0_sum<<<1, 256, 0, stream>>>(Gpart, G);
    k1<<<NROWS / 16, 256, 0, stream>>>(x, Apf, s1b);
    kc_scale<<<NROWS / 8, 512, 0, stream>>>(s1b, G, s1p);
    k2_gemm2<<<16384, 512, 0, stream>>>(s1p, Bp, out);
}

// Round 10
// 171.654 us; speedup vs baseline: 1.8055x; 1.8055x over previous
//
#include <hip/hip_runtime.h>
#include <hip/hip_bf16.h>

#define NROWS 16384
#define DIN   4096
#define DOUT  4096
#define RNK   64
#define EPSF  1e-7f

typedef float  f32x4  __attribute__((ext_vector_type(4)));
typedef __bf16 bf16x4 __attribute__((ext_vector_type(4)));
typedef __bf16 bf16x8 __attribute__((ext_vector_type(8)));

__device__ __forceinline__ bf16x8 cvt8(f32x4 a, f32x4 b) {
    bf16x8 r;
    r[0]=(__bf16)a.x; r[1]=(__bf16)a.y; r[2]=(__bf16)a.z; r[3]=(__bf16)a.w;
    r[4]=(__bf16)b.x; r[5]=(__bf16)b.y; r[6]=(__bf16)b.z; r[7]=(__bf16)b.w;
    return r;
}
__device__ __forceinline__ bf16x4 cvt4(f32x4 v) {
    bf16x4 r;
    r[0]=(__bf16)v.x; r[1]=(__bf16)v.y; r[2]=(__bf16)v.z; r[3]=(__bf16)v.w;
    return r;
}

__device__ __forceinline__ void gl_lds16(const void* g, void* l) {
    __builtin_amdgcn_global_load_lds(
        (const __attribute__((address_space(1))) void*)g,
        (__attribute__((address_space(3))) void*)l, 16, 0, 0);
}

// ---------------------------------------------------------------------------
// KA: Apf = Aw in bf16 MFMA-fragment order.
// Chunk (kt, ng): Apf[(kt*4+ng)*512 + l*8 + j] = Aw[ng*16+(l&15)][kt*32+(l>>4)*8+j]
// ---------------------------------------------------------------------------
__global__ __launch_bounds__(512, 2)
void ka_apf(const float* __restrict__ Aw, __bf16* __restrict__ Apf) {
    const int kt = blockIdx.x;           // 128 K-chunks of 32
    const int t = threadIdx.x;
    const int ng = t >> 7, le = (t >> 1) & 63, h = t & 1;
    f32x4 v = *(const f32x4*)&Aw[(size_t)(ng*16 + (le&15)) * DIN + kt*32 + (le>>4)*8 + h*4];
    *(bf16x4*)&Apf[((size_t)(kt*4 + ng))*512 + le*8 + h*4] = cvt4(v);
}

// ---------------------------------------------------------------------------
// KB: B -> bf16 plain copy + Gram partials (G = B^T B).
// ---------------------------------------------------------------------------
__global__ __launch_bounds__(512, 4)
void kb_gram(const float* __restrict__ Bw, __bf16* __restrict__ Bp,
             float* __restrict__ Gpart) {
    __shared__ __bf16 bs[256][72];
    const int t = threadIdx.x;
    const int jb = blockIdx.x * 256;
    {
        const int j0 = t >> 1, c0 = (t & 1) * 32;
        #pragma unroll
        for (int u = 0; u < 4; ++u) {
            f32x4 v0 = *(const f32x4*)&Bw[(size_t)(jb + j0) * RNK + c0 + 8*u];
            f32x4 v1 = *(const f32x4*)&Bw[(size_t)(jb + j0) * RNK + c0 + 8*u + 4];
            bf16x8 p = cvt8(v0, v1);
            *(bf16x8*)&bs[j0][c0 + 8*u] = p;
            *(bf16x8*)&Bp[(size_t)(jb + j0) * RNK + c0 + 8*u] = p;
        }
    }
    __syncthreads();
    const int r = t & 63, rp = (t >> 6) * 8;
    float acc[8] = {0,0,0,0,0,0,0,0};
    for (int j = 0; j < 256; ++j) {
        float s = (float)bs[j][r];
        bf16x8 v = *(const bf16x8*)&bs[j][rp];   // wave-uniform: broadcast
        #pragma unroll
        for (int u = 0; u < 8; ++u) acc[u] += s * (float)v[u];
    }
    #pragma unroll
    for (int u = 0; u < 8; ++u)
        Gpart[(size_t)blockIdx.x * 4096 + r * 64 + rp + u] = acc[u];
}

__global__ void kc0_sum(const float* __restrict__ Gpart, float* __restrict__ G) {
    const int t = threadIdx.x;
    #pragma unroll
    for (int v = 0; v < 4; ++v) {
        f32x4 a = {0.f, 0.f, 0.f, 0.f};
        for (int b = 0; b < 16; ++b)
            a += *(const f32x4*)&Gpart[(size_t)b * 4096 + t * 16 + v * 4];
        *(f32x4*)&G[t * 16 + v * 4] = a;
    }
}

// ---------------------------------------------------------------------------
// K1: s1b = bf16( sinh(||x||)/||x|| * x @ Aw^T ).
// 1024 blocks x 256 thr (4 waves). 16 rows x BK=128 f32 tile (8 KB) staged via
// global_load_lds_dwordx4 into a 4-buffer ring (depth-2 prefetch). Raw
// s_barrier + counted vmcnt — the stage stream NEVER drains to 0 in the loop.
// Source pre-swizzled (slot ^= row&15) so linear-LDS + swizzled ds_read is
// bank-conflict-free (rule: both-sides-or-neither). ssq fused into fragment
// reads (f32, before cvt). ap loads issued FIRST so compiler's pre-MFMA wait
// leaves the newest stage in flight.
// ---------------------------------------------------------------------------
__global__ __launch_bounds__(256, 4)
void k1(const float* __restrict__ x, const __bf16* __restrict__ Apf,
        __bf16* __restrict__ s1b) {
    __shared__ __align__(16) char smem[4 * 8192 + 64];
    float* rowss = (float*)(smem + 32768);

    const int t = threadIdx.x, l = t & 63, w = t >> 6;
    const int brow = blockIdx.x * 16;
    const int h  = l >> 5;               // half-wave -> row within instr
    const int p  = l & 31;               // phys 16B slot
    const int r0 = w * 4 + h;            // instr-0 row (0..15)
    const int r1 = w * 4 + 2 + h;        // instr-1 row
    const int sl0 = p ^ (r0 & 15);       // pre-swizzled logical slot
    const int sl1 = p ^ (r1 & 15);
    const float* g0 = &x[(size_t)(brow + r0) * DIN + sl0 * 4];
    const float* g1 = &x[(size_t)(brow + r1) * DIN + sl1 * 4];
    const int lb0 = (w * 2 + 0) * 1024;  // wave-uniform LDS dest (lane*16 by HW)
    const int lb1 = (w * 2 + 1) * 1024;

    const int frow = l & 15;             // fragment row
    const int fls  = (l >> 4) * 2;       // fragment slot offset

    f32x4 acc = {0.f, 0.f, 0.f, 0.f};
    float ssq = 0.f;

    // prologue: stage tiles 0,1
    gl_lds16(g0,       smem + 0 * 8192 + lb0);
    gl_lds16(g1,       smem + 0 * 8192 + lb1);
    gl_lds16(g0 + 128, smem + 1 * 8192 + lb0);
    gl_lds16(g1 + 128, smem + 1 * 8192 + lb1);

    #pragma unroll 1
    for (int tt = 0; tt < 32; ++tt) {
        // A fragments for tile tt (L2) — issued before stages on purpose
        const size_t ab = ((size_t)(tt * 4) * 4 + w) * 512 + (size_t)l * 8;
        bf16x8 ap0 = *(const bf16x8*)&Apf[ab];
        bf16x8 ap1 = *(const bf16x8*)&Apf[ab + 4 * 512];
        bf16x8 ap2 = *(const bf16x8*)&Apf[ab + 8 * 512];
        bf16x8 ap3 = *(const bf16x8*)&Apf[ab + 12 * 512];
        // stage tile tt+2
        if (tt + 2 < 32) {
            char* nb = smem + ((tt + 2) & 3) * 8192;
            gl_lds16(g0 + (size_t)(tt + 2) * 128, nb + lb0);
            gl_lds16(g1 + (size_t)(tt + 2) * 128, nb + lb1);
        }
        __builtin_amdgcn_sched_barrier(0);
        // younger-than-stage(tt): stage(tt+1)[2] + ap[4] + stage(tt+2)[2]
        if (tt < 30)      asm volatile("s_waitcnt vmcnt(8)" ::: "memory");
        else if (tt < 31) asm volatile("s_waitcnt vmcnt(6)" ::: "memory");
        else              asm volatile("s_waitcnt vmcnt(4)" ::: "memory");
        __builtin_amdgcn_s_barrier();
        __builtin_amdgcn_sched_barrier(0);

        const char* buf = smem + (tt & 3) * 8192;
        #pragma unroll
        for (int ks = 0; ks < 4; ++ks) {
            const int ls = ks * 8 + fls;
            f32x4 v0 = *(const f32x4*)(buf + frow * 512 + ((ls    ) ^ frow) * 16);
            f32x4 v1 = *(const f32x4*)(buf + frow * 512 + ((ls + 1) ^ frow) * 16);
            ssq += v0.x*v0.x + v0.y*v0.y + v0.z*v0.z + v0.w*v0.w
                 + v1.x*v1.x + v1.y*v1.y + v1.z*v1.z + v1.w*v1.w;
            bf16x8 xf = cvt8(v0, v1);
            bf16x8 ap = (ks == 0) ? ap0 : (ks == 1) ? ap1 : (ks == 2) ? ap2 : ap3;
            acc = __builtin_amdgcn_mfma_f32_16x16x32_bf16(ap, xf, acc, 0, 0, 0);
        }
    }

    // every wave read its full rows -> full ssq; reduce the 4 lanes per row
    float v = ssq;
    v += __shfl_xor(v, 16);
    v += __shfl_xor(v, 32);
    if (t < 16) rowss[t] = v;            // wave 0, frow == l == t
    __syncthreads();

    const float sq = rowss[frow];
    const float vn = fmaxf(sqrtf(sq), EPSF);
    const float sc = sinhf(vn) / vn;
    f32x4 o = acc * sc;
    // D map: col(lane&15)=x-row, row=(l>>4)*4+q = out-col within n-group w
    *(bf16x4*)&s1b[(size_t)(brow + frow) * RNK + w * 16 + (l >> 4) * 4] = cvt4(o);
}

// ---------------------------------------------------------------------------
// KC: r2 = s1^T G s1 ; g = 0.25*acosh(...)/max(r,eps); s1p = bf16(g * s1).
// ---------------------------------------------------------------------------
__global__ __launch_bounds__(512, 4)
void kc_scale(const __bf16* __restrict__ s1b, const float* __restrict__ G,
              __bf16* __restrict__ s1p) {
    __shared__ float Gs[64][64];
    __shared__ float sr[8][64];
    const int t = threadIdx.x, l = t & 63, w = t >> 6;
    {
        float* gf = &Gs[0][0];
        *(f32x4*)&gf[t * 8]     = *(const f32x4*)&G[t * 8];
        *(f32x4*)&gf[t * 8 + 4] = *(const f32x4*)&G[t * 8 + 4];
    }
    const int row = blockIdx.x * 8 + w;
    const float a = (float)s1b[(size_t)row * RNK + l];
    sr[w][l] = a;
    __syncthreads();

    float y = 0.f;
    #pragma unroll 8
    for (int r = 0; r < 64; ++r) y += Gs[r][l] * sr[w][r];

    float q = a * y;
    q += __shfl_xor(q, 1);  q += __shfl_xor(q, 2);  q += __shfl_xor(q, 4);
    q += __shfl_xor(q, 8);  q += __shfl_xor(q, 16); q += __shfl_xor(q, 32);

    const float r2 = q;
    const float rn = sqrtf(r2);
    const float g = 0.25f * acoshf(fmaxf(sqrtf(1.f + r2), 1.f + EPSF))
                          / fmaxf(rn, EPSF);
    s1p[(size_t)row * RNK + l] = (__bf16)(g * a);
}

// ---------------------------------------------------------------------------
// K2: out = s1p @ Bp^T. 64x64 tile/block, 16384 blocks (proven r2/r9 tail).
// ---------------------------------------------------------------------------
__global__ __launch_bounds__(512, 4)
void k2_gemm2(const __bf16* __restrict__ s1p, const __bf16* __restrict__ Bp,
              float* __restrict__ out) {
    __shared__ __bf16 ss[64][72];
    __shared__ __bf16 bsh[64][72];
    const int t = threadIdx.x, l = t & 63, w = t >> 6;
    const int rt = blockIdx.x >> 6;
    const int ct = blockIdx.x & 63;
    const int brow = rt * 64, bcol = ct * 64;

    {
        const int row = t >> 3, c = (t & 7) * 8;
        *(bf16x8*)&ss[row][c]  = *(const bf16x8*)&s1p[(size_t)(brow + row) * RNK + c];
        *(bf16x8*)&bsh[row][c] = *(const bf16x8*)&Bp[(size_t)(bcol + row) * RNK + c];
    }
    __syncthreads();

    const int m0 = (w & 3) * 16;
    const int n0 = (w >> 2) * 32;
    const int frow = l & 15;
    const int koff = (l >> 4) * 8;

    f32x4 a0 = {0.f,0.f,0.f,0.f}, a1 = {0.f,0.f,0.f,0.f};
    #pragma unroll
    for (int ks = 0; ks < 2; ++ks) {
        bf16x8 af = *(const bf16x8*)&ss[m0 + frow][ks*32 + koff];
        bf16x8 b0 = *(const bf16x8*)&bsh[n0 + frow][ks*32 + koff];
        bf16x8 b1 = *(const bf16x8*)&bsh[n0 + 16 + frow][ks*32 + koff];
        a0 = __builtin_amdgcn_mfma_f32_16x16x32_bf16(af, b0, a0, 0, 0, 0);
        a1 = __builtin_amdgcn_mfma_f32_16x16x32_bf16(af, b1, a1, 0, 0, 0);
    }

    #pragma unroll
    for (int q = 0; q < 4; ++q) {
        const int row = m0 + (l >> 4) * 4 + q;
        const size_t ob = (size_t)(brow + row) * DOUT + bcol;
        out[ob + n0 + frow]      = a0[q];
        out[ob + n0 + 16 + frow] = a1[q];
    }
}

extern "C" void kernel_launch(void* const* d_in, const int* in_sizes, int n_in,
                              void* d_out, int out_size, void* d_ws, size_t ws_size,
                              hipStream_t stream) {
    const float* x  = (const float*)d_in[0];   // (16384, 4096)
    const float* Aw = (const float*)d_in[1];   // (64, 4096)
    const float* Bw = (const float*)d_in[2];   // (4096, 64)
    float* out = (float*)d_out;

    char* ws = (char*)d_ws;
    __bf16* Apf   = (__bf16*)(ws);                  // 512 KB (fragment order)
    __bf16* Bp    = (__bf16*)(ws + 0x080000);       // 512 KB
    float*  Gpart = (float*)(ws + 0x100000);        // 256 KB
    float*  G     = (float*)(ws + 0x140000);        // 16 KB
    __bf16* s1b   = (__bf16*)(ws + 0x150000);       // 2 MB
    __bf16* s1p   = (__bf16*)(ws + 0x350000);       // 2 MB

    ka_apf<<<128, 512, 0, stream>>>(Aw, Apf);
    kb_gram<<<16, 512, 0, stream>>>(Bw, Bp, Gpart);
    kc0_sum<<<1, 256, 0, stream>>>(Gpart, G);
    k1<<<NROWS / 16, 256, 0, stream>>>(x, Apf, s1b);
    kc_scale<<<NROWS / 8, 512, 0, stream>>>(s1b, G, s1p);
    k2_gemm2<<<16384, 512, 0, stream>>>(s1p, Bp, out);
}